// Round 1
// baseline (15253.102 us; speedup 1.0000x reference)
//
#include <hip/hip_runtime.h>
#include <math.h>

#define BATCH 1024
#define IN_F  1024
#define OUT_F 2048
#define LAMBD 0.2f
#define TOL   1e-4f
#define MAX_ITERS 100

// GEMM tiling: 64x64 C-tile, BK=16, 256 threads, 4x4 micro-tile per thread.
#define BM 64
#define BN 64
#define BK 16
#define TM 4
#define TN 4
#define LDA (BM + 4)   // pad to keep float4 alignment (68*4 bytes % 16 == 0) and break bank strides
#define LDB (BN + 4)

// ---------------------------------------------------------------------------
// init: zero v, u, encoded (d_out first part), solved flags
// ---------------------------------------------------------------------------
__global__ void init_kernel(float4* __restrict__ v, float4* __restrict__ u,
                            float4* __restrict__ enc, int* __restrict__ solved) {
    const int i = blockIdx.x * blockDim.x + threadIdx.x;
    const int n4 = BATCH * OUT_F / 4;
    const float4 z = make_float4(0.f, 0.f, 0.f, 0.f);
    if (i < n4) { v[i] = z; u[i] = z; enc[i] = z; }
    if (i < BATCH) solved[i] = 0;
}

// ---------------------------------------------------------------------------
// NT GEMM: C[M,N] = A[M,K] * B[N,K]^T   (both K-contiguous). Used for Ab = x @ w^T.
// ---------------------------------------------------------------------------
__global__ __launch_bounds__(256)
void gemm_nt(const float* __restrict__ A, const float* __restrict__ B,
             float* __restrict__ C, int M, int N, int K) {
    __shared__ float As[BK][LDA];
    __shared__ float Bs[BK][LDB];
    const int tid = threadIdx.x;
    const int tx = tid & 15, ty = tid >> 4;
    const int m0 = blockIdx.y * BM;
    const int n0 = blockIdx.x * BN;
    const int lr = tid >> 2;            // 0..63: row within tile
    const int lk = (tid & 3) * 4;       // k-subgroup (4 floats)

    float acc[TM][TN] = {};

    for (int k0 = 0; k0 < K; k0 += BK) {
        const float4 a4 = *(const float4*)&A[(size_t)(m0 + lr) * K + k0 + lk];
        const float4 b4 = *(const float4*)&B[(size_t)(n0 + lr) * K + k0 + lk];
        __syncthreads();
        As[lk + 0][lr] = a4.x; As[lk + 1][lr] = a4.y; As[lk + 2][lr] = a4.z; As[lk + 3][lr] = a4.w;
        Bs[lk + 0][lr] = b4.x; Bs[lk + 1][lr] = b4.y; Bs[lk + 2][lr] = b4.z; Bs[lk + 3][lr] = b4.w;
        __syncthreads();
#pragma unroll
        for (int kk = 0; kk < BK; ++kk) {
            const float4 av = *(const float4*)&As[kk][ty * TM];
            const float4 bv = *(const float4*)&Bs[kk][tx * TN];
            const float ar[4] = {av.x, av.y, av.z, av.w};
            const float br[4] = {bv.x, bv.y, bv.z, bv.w};
#pragma unroll
            for (int i = 0; i < TM; ++i)
#pragma unroll
                for (int j = 0; j < TN; ++j)
                    acc[i][j] = fmaf(ar[i], br[j], acc[i][j]);
        }
    }
#pragma unroll
    for (int i = 0; i < TM; ++i) {
        float4 o = make_float4(acc[i][0], acc[i][1], acc[i][2], acc[i][3]);
        *(float4*)&C[(size_t)(m0 + ty * TM + i) * N + n0 + tx * TN] = o;
    }
}

// ---------------------------------------------------------------------------
// NN GEMM with fused b_eff = Ab + v - u, and 64-row-tile skip when all solved.
// xk[M,N] = (Ab+v-u)[M,K] * Minv[K,N]   (M=1024, N=K=2048)
// ---------------------------------------------------------------------------
__global__ __launch_bounds__(256)
void xk_gemm(const float* __restrict__ Ab, const float* __restrict__ v,
             const float* __restrict__ u, const float* __restrict__ Bm,
             float* __restrict__ xk, const int* __restrict__ solved) {
    constexpr int M = BATCH, N = OUT_F, K = OUT_F;
    (void)M;
    __shared__ float As[BK][LDA];
    __shared__ float Bs[BK][LDB];
    __shared__ int s_active;
    const int tid = threadIdx.x;
    const int m0 = blockIdx.y * BM;
    const int n0 = blockIdx.x * BN;

    if (tid == 0) s_active = 0;
    __syncthreads();
    if (tid < BM && solved[m0 + tid] == 0) s_active = 1;   // benign race
    __syncthreads();
    if (!s_active) return;                                  // whole tile frozen

    const int tx = tid & 15, ty = tid >> 4;
    const int lr = tid >> 2;
    const int lk = (tid & 3) * 4;
    const int kb = tid >> 4;            // 0..15 for B staging
    const int nb = (tid & 15) * 4;

    float acc[TM][TN] = {};

    for (int k0 = 0; k0 < K; k0 += BK) {
        const size_t aoff = (size_t)(m0 + lr) * K + k0 + lk;
        const float4 ab4 = *(const float4*)&Ab[aoff];
        const float4 v4  = *(const float4*)&v[aoff];
        const float4 u4  = *(const float4*)&u[aoff];
        const float4 a4 = make_float4(ab4.x + v4.x - u4.x, ab4.y + v4.y - u4.y,
                                      ab4.z + v4.z - u4.z, ab4.w + v4.w - u4.w);
        const float4 b4 = *(const float4*)&Bm[(size_t)(k0 + kb) * N + n0 + nb];
        __syncthreads();
        As[lk + 0][lr] = a4.x; As[lk + 1][lr] = a4.y; As[lk + 2][lr] = a4.z; As[lk + 3][lr] = a4.w;
        *(float4*)&Bs[kb][nb] = b4;
        __syncthreads();
#pragma unroll
        for (int kk = 0; kk < BK; ++kk) {
            const float4 av = *(const float4*)&As[kk][ty * TM];
            const float4 bv = *(const float4*)&Bs[kk][tx * TN];
            const float ar[4] = {av.x, av.y, av.z, av.w};
            const float br[4] = {bv.x, bv.y, bv.z, bv.w};
#pragma unroll
            for (int i = 0; i < TM; ++i)
#pragma unroll
                for (int j = 0; j < TN; ++j)
                    acc[i][j] = fmaf(ar[i], br[j], acc[i][j]);
        }
    }
#pragma unroll
    for (int i = 0; i < TM; ++i) {
        float4 o = make_float4(acc[i][0], acc[i][1], acc[i][2], acc[i][3]);
        *(float4*)&xk[(size_t)(m0 + ty * TM + i) * N + n0 + tx * TN] = o;
    }
}

// ---------------------------------------------------------------------------
// Plain NN GEMM: C[M,N] = A[M,K] * B[K,N]. Used for decoded = encoded @ w.
// ---------------------------------------------------------------------------
__global__ __launch_bounds__(256)
void gemm_nn(const float* __restrict__ A, const float* __restrict__ B,
             float* __restrict__ C, int M, int N, int K) {
    __shared__ float As[BK][LDA];
    __shared__ float Bs[BK][LDB];
    const int tid = threadIdx.x;
    const int tx = tid & 15, ty = tid >> 4;
    const int m0 = blockIdx.y * BM;
    const int n0 = blockIdx.x * BN;
    const int lr = tid >> 2;
    const int lk = (tid & 3) * 4;
    const int kb = tid >> 4;
    const int nb = (tid & 15) * 4;

    float acc[TM][TN] = {};

    for (int k0 = 0; k0 < K; k0 += BK) {
        const float4 a4 = *(const float4*)&A[(size_t)(m0 + lr) * K + k0 + lk];
        const float4 b4 = *(const float4*)&B[(size_t)(k0 + kb) * N + n0 + nb];
        __syncthreads();
        As[lk + 0][lr] = a4.x; As[lk + 1][lr] = a4.y; As[lk + 2][lr] = a4.z; As[lk + 3][lr] = a4.w;
        *(float4*)&Bs[kb][nb] = b4;
        __syncthreads();
#pragma unroll
        for (int kk = 0; kk < BK; ++kk) {
            const float4 av = *(const float4*)&As[kk][ty * TM];
            const float4 bv = *(const float4*)&Bs[kk][tx * TN];
            const float ar[4] = {av.x, av.y, av.z, av.w};
            const float br[4] = {bv.x, bv.y, bv.z, bv.w};
#pragma unroll
            for (int i = 0; i < TM; ++i)
#pragma unroll
                for (int j = 0; j < TN; ++j)
                    acc[i][j] = fmaf(ar[i], br[j], acc[i][j]);
        }
    }
#pragma unroll
    for (int i = 0; i < TM; ++i) {
        float4 o = make_float4(acc[i][0], acc[i][1], acc[i][2], acc[i][3]);
        *(float4*)&C[(size_t)(m0 + ty * TM + i) * N + n0 + tx * TN] = o;
    }
}

// ---------------------------------------------------------------------------
// Per-row ADMM update: softshrink, u update, convergence check, freeze+emit.
// One block (256 threads) per batch row; 8 elements per thread.
// ---------------------------------------------------------------------------
__global__ __launch_bounds__(256)
void update_kernel(const float* __restrict__ xk, float* __restrict__ v,
                   float* __restrict__ u, float* __restrict__ enc,
                   int* __restrict__ solved) {
    const int row = blockIdx.x;
    if (solved[row]) return;
    const int t = threadIdx.x;

    const float* xkr = xk + (size_t)row * OUT_F;
    float* vr = v + (size_t)row * OUT_F;
    float* ur = u + (size_t)row * OUT_F;

    float vn[8];
    float dx2 = 0.f, xn2 = 0.f;
#pragma unroll
    for (int i = 0; i < 8; ++i) {
        const int c = t + i * 256;
        const float xkv = xkr[c];
        const float uv  = ur[c];
        const float vp  = vr[c];
        const float z   = xkv + uv;
        const float az  = fabsf(z) - LAMBD;
        const float vnew = az > 0.f ? copysignf(az, z) : 0.f;
        ur[c] = uv + xkv - vnew;
        vr[c] = vnew;
        vn[i] = vnew;
        const float d = vnew - vp;
        dx2 += d * d;
        xn2 += vnew * vnew;
    }

    // wave (64-lane) reduction, then across 4 waves via LDS
#pragma unroll
    for (int o = 32; o > 0; o >>= 1) {
        dx2 += __shfl_down(dx2, o);
        xn2 += __shfl_down(xn2, o);
    }
    __shared__ float sdx[4], sxn[4];
    __shared__ float s_conv;
    if ((t & 63) == 0) { sdx[t >> 6] = dx2; sxn[t >> 6] = xn2; }
    __syncthreads();
    if (t == 0) {
        const float dxt = sqrtf(sdx[0] + sdx[1] + sdx[2] + sdx[3]);
        const float xnt = sqrtf(sxn[0] + sxn[1] + sxn[2] + sxn[3]);
        const bool conv = (dxt / xnt) < TOL;   // NaN (0/0) -> false, matches jnp
        s_conv = conv ? 1.f : 0.f;
        if (conv) solved[row] = 1;
    }
    __syncthreads();
    if (s_conv != 0.f) {
        float* er = enc + (size_t)row * OUT_F;
#pragma unroll
        for (int i = 0; i < 8; ++i) er[t + i * 256] = vn[i];
    }
}

// ---------------------------------------------------------------------------
extern "C" void kernel_launch(void* const* d_in, const int* in_sizes, int n_in,
                              void* d_out, int out_size, void* d_ws, size_t ws_size,
                              hipStream_t stream) {
    (void)in_sizes; (void)n_in; (void)out_size; (void)ws_size;
    const float* x    = (const float*)d_in[0];   // 1024 x 1024
    const float* w    = (const float*)d_in[1];   // 2048 x 1024
    const float* Minv = (const float*)d_in[2];   // 2048 x 2048

    float* enc = (float*)d_out;                  // 1024 x 2048
    float* dec = enc + (size_t)BATCH * OUT_F;    // 1024 x 1024

    float* Ab = (float*)d_ws;                    // 1024 x 2048
    float* v  = Ab + (size_t)BATCH * OUT_F;
    float* u  = v  + (size_t)BATCH * OUT_F;
    float* xk = u  + (size_t)BATCH * OUT_F;
    int* solved = (int*)(xk + (size_t)BATCH * OUT_F);

    // zero v, u, encoded, solved
    {
        const int n4 = BATCH * OUT_F / 4;
        init_kernel<<<(n4 + 255) / 256, 256, 0, stream>>>(
            (float4*)v, (float4*)u, (float4*)enc, solved);
    }

    // Ab = x @ w^T : M=1024, N=2048, K=1024
    gemm_nt<<<dim3(OUT_F / BN, BATCH / BM), 256, 0, stream>>>(x, w, Ab, BATCH, OUT_F, IN_F);

    for (int it = 0; it < MAX_ITERS; ++it) {
        xk_gemm<<<dim3(OUT_F / BN, BATCH / BM), 256, 0, stream>>>(Ab, v, u, Minv, xk, solved);
        update_kernel<<<BATCH, 256, 0, stream>>>(xk, v, u, enc, solved);
    }

    // decoded = encoded @ w : M=1024, N=1024, K=2048
    gemm_nn<<<dim3(IN_F / BN, BATCH / BM), 256, 0, stream>>>(enc, w, dec, BATCH, IN_F, OUT_F);
}

// Round 2
// 6026.571 us; speedup vs baseline: 2.5310x; 2.5310x over previous
//
#include <hip/hip_runtime.h>
#include <math.h>

#define BATCH 1024
#define IN_F  1024
#define OUT_F 2048
#define LAMBD 0.2f
#define TOL   1e-4f
#define MAX_ITERS 100

#define KSPLIT 4
#define KCHUNK (OUT_F / KSPLIT)   // 512

typedef _Float16 half8 __attribute__((ext_vector_type(8)));
typedef _Float16 half4 __attribute__((ext_vector_type(4)));
typedef float    floatx16 __attribute__((ext_vector_type(16)));

#define GLOAD_LDS16(g, l) __builtin_amdgcn_global_load_lds(              \
    (const __attribute__((address_space(1))) void*)(g),                  \
    (__attribute__((address_space(3))) void*)(l), 16, 0, 0)

// fp32 fallback GEMM tiling (used for the two one-shot GEMMs)
#define BM 64
#define BN 64
#define BK 16
#define TM 4
#define TN 4
#define LDA (BM + 4)
#define LDB (BN + 4)

// ---------------------------------------------------------------------------
__global__ void init_kernel(float4* __restrict__ v, float4* __restrict__ u,
                            float4* __restrict__ enc, int* __restrict__ solved) {
    const int i = blockIdx.x * blockDim.x + threadIdx.x;
    const int n4 = BATCH * OUT_F / 4;
    const float4 z = make_float4(0.f, 0.f, 0.f, 0.f);
    if (i < n4) { v[i] = z; u[i] = z; enc[i] = z; }
    if (i < BATCH) solved[i] = 0;
}

// ---------------------------------------------------------------------------
// Split + transpose M_inv (2048x2048 fp32, row-major [k][n]) into
// BhT/BlT fp16 [n][k] (K-major per row, matching MFMA staging).
// ---------------------------------------------------------------------------
__global__ __launch_bounds__(256)
void split_b_kernel(const float* __restrict__ B, _Float16* __restrict__ BhT,
                    _Float16* __restrict__ BlT) {
    __shared__ float tile[32][33];
    const int tid = threadIdx.x;
    const int k0 = blockIdx.y * 32;
    const int n0 = blockIdx.x * 32;
    const int r = tid >> 3;
    const int c4 = (tid & 7) * 4;
    const float4 b4 = *(const float4*)&B[(size_t)(k0 + r) * OUT_F + n0 + c4];
    tile[r][c4 + 0] = b4.x; tile[r][c4 + 1] = b4.y;
    tile[r][c4 + 2] = b4.z; tile[r][c4 + 3] = b4.w;
    __syncthreads();
    half4 h, l;
#pragma unroll
    for (int j = 0; j < 4; ++j) {
        const float x = tile[c4 + j][r];
        const _Float16 hi = (_Float16)x;
        h[j] = hi;
        l[j] = (_Float16)(x - (float)hi);
    }
    const size_t o = (size_t)(n0 + r) * OUT_F + k0 + c4;
    *(half4*)&BhT[o] = h;
    *(half4*)&BlT[o] = l;
}

// ---------------------------------------------------------------------------
// NT GEMM fp32: Ab = x @ w^T, with epilogue split Ah/Al = fp16(Ab) (v=u=0 at t0)
// ---------------------------------------------------------------------------
__global__ __launch_bounds__(256)
void gemm_nt(const float* __restrict__ A, const float* __restrict__ B,
             float* __restrict__ C, _Float16* __restrict__ Ah,
             _Float16* __restrict__ Al, int M, int N, int K) {
    __shared__ float As[BK][LDA];
    __shared__ float Bs[BK][LDB];
    const int tid = threadIdx.x;
    const int tx = tid & 15, ty = tid >> 4;
    const int m0 = blockIdx.y * BM;
    const int n0 = blockIdx.x * BN;
    const int lr = tid >> 2;
    const int lk = (tid & 3) * 4;

    float acc[TM][TN] = {};

    for (int k0 = 0; k0 < K; k0 += BK) {
        const float4 a4 = *(const float4*)&A[(size_t)(m0 + lr) * K + k0 + lk];
        const float4 b4 = *(const float4*)&B[(size_t)(n0 + lr) * K + k0 + lk];
        __syncthreads();
        As[lk + 0][lr] = a4.x; As[lk + 1][lr] = a4.y; As[lk + 2][lr] = a4.z; As[lk + 3][lr] = a4.w;
        Bs[lk + 0][lr] = b4.x; Bs[lk + 1][lr] = b4.y; Bs[lk + 2][lr] = b4.z; Bs[lk + 3][lr] = b4.w;
        __syncthreads();
#pragma unroll
        for (int kk = 0; kk < BK; ++kk) {
            const float4 av = *(const float4*)&As[kk][ty * TM];
            const float4 bv = *(const float4*)&Bs[kk][tx * TN];
            const float ar[4] = {av.x, av.y, av.z, av.w};
            const float br[4] = {bv.x, bv.y, bv.z, bv.w};
#pragma unroll
            for (int i = 0; i < TM; ++i)
#pragma unroll
                for (int j = 0; j < TN; ++j)
                    acc[i][j] = fmaf(ar[i], br[j], acc[i][j]);
        }
    }
#pragma unroll
    for (int i = 0; i < TM; ++i) {
        const size_t o = (size_t)(m0 + ty * TM + i) * N + n0 + tx * TN;
        float4 ov = make_float4(acc[i][0], acc[i][1], acc[i][2], acc[i][3]);
        *(float4*)&C[o] = ov;
        half4 h, l;
#pragma unroll
        for (int j = 0; j < 4; ++j) {
            const float x = acc[i][j];
            const _Float16 hi = (_Float16)x;
            h[j] = hi;
            l[j] = (_Float16)(x - (float)hi);
        }
        *(half4*)&Ah[o] = h;
        *(half4*)&Al[o] = l;
    }
}

// ---------------------------------------------------------------------------
// MFMA split-fp16 GEMM: xk_part[kz] = Aeff[:, kz*512:(kz+1)*512] @ Minv[kz...]
// 128x128 tile, 4 waves of 2x2 32x32x16 accumulators, 3-term split product.
// ---------------------------------------------------------------------------
__global__ __launch_bounds__(256)
void xk_mfma(const _Float16* __restrict__ Ah, const _Float16* __restrict__ Al,
             const _Float16* __restrict__ BhT, const _Float16* __restrict__ BlT,
             float* __restrict__ xkp, const int* __restrict__ solved) {
    __shared__ _Float16 sAh[128 * 16];
    __shared__ _Float16 sAl[128 * 16];
    __shared__ _Float16 sBh[128 * 16];
    __shared__ _Float16 sBl[128 * 16];
    const int tid = threadIdx.x;
    const int m0 = blockIdx.y * 128;
    const int n0 = blockIdx.x * 128;
    const int kz = blockIdx.z;

    __shared__ int s_active;
    if (tid == 0) s_active = 0;
    __syncthreads();
    if (tid < 128 && solved[m0 + tid] == 0) s_active = 1;   // benign race
    __syncthreads();
    if (!s_active) return;

    const int wv = tid >> 6;
    const int ln = tid & 63;
    const int half = ln >> 5;
    const int l31 = ln & 31;
    const int wm = (wv >> 1) * 64;
    const int wn = (wv & 1) * 64;

    // staging: each wave fills a 32-row strip of each tile; lane -> (row, k-half)
    const int grow = wv * 32 + (ln >> 1);
    const int scol = (ln & 1) * 8;
    const _Float16* gAh = Ah  + (size_t)(m0 + grow) * OUT_F + kz * KCHUNK + scol;
    const _Float16* gAl = Al  + (size_t)(m0 + grow) * OUT_F + kz * KCHUNK + scol;
    const _Float16* gBh = BhT + (size_t)(n0 + grow) * OUT_F + kz * KCHUNK + scol;
    const _Float16* gBl = BlT + (size_t)(n0 + grow) * OUT_F + kz * KCHUNK + scol;
    _Float16* lAh = sAh + wv * 512 + ln * 8;
    _Float16* lAl = sAl + wv * 512 + ln * 8;
    _Float16* lBh = sBh + wv * 512 + ln * 8;
    _Float16* lBl = sBl + wv * 512 + ln * 8;

    floatx16 acc[2][2];
#pragma unroll
    for (int a = 0; a < 2; ++a)
#pragma unroll
        for (int b = 0; b < 2; ++b)
#pragma unroll
            for (int r = 0; r < 16; ++r) acc[a][b][r] = 0.f;

    for (int ks = 0; ks < KCHUNK; ks += 16) {
        __syncthreads();
        GLOAD_LDS16(gAh + ks, lAh);
        GLOAD_LDS16(gAl + ks, lAl);
        GLOAD_LDS16(gBh + ks, lBh);
        GLOAD_LDS16(gBl + ks, lBl);
        __syncthreads();

        const half8 ah0 = *(const half8*)&sAh[(wm + l31) * 16 + half * 8];
        const half8 ah1 = *(const half8*)&sAh[(wm + 32 + l31) * 16 + half * 8];
        const half8 al0 = *(const half8*)&sAl[(wm + l31) * 16 + half * 8];
        const half8 al1 = *(const half8*)&sAl[(wm + 32 + l31) * 16 + half * 8];
        const half8 bh0 = *(const half8*)&sBh[(wn + l31) * 16 + half * 8];
        const half8 bh1 = *(const half8*)&sBh[(wn + 32 + l31) * 16 + half * 8];
        const half8 bl0 = *(const half8*)&sBl[(wn + l31) * 16 + half * 8];
        const half8 bl1 = *(const half8*)&sBl[(wn + 32 + l31) * 16 + half * 8];

        acc[0][0] = __builtin_amdgcn_mfma_f32_32x32x16_f16(ah0, bh0, acc[0][0], 0, 0, 0);
        acc[0][1] = __builtin_amdgcn_mfma_f32_32x32x16_f16(ah0, bh1, acc[0][1], 0, 0, 0);
        acc[1][0] = __builtin_amdgcn_mfma_f32_32x32x16_f16(ah1, bh0, acc[1][0], 0, 0, 0);
        acc[1][1] = __builtin_amdgcn_mfma_f32_32x32x16_f16(ah1, bh1, acc[1][1], 0, 0, 0);
        acc[0][0] = __builtin_amdgcn_mfma_f32_32x32x16_f16(ah0, bl0, acc[0][0], 0, 0, 0);
        acc[0][1] = __builtin_amdgcn_mfma_f32_32x32x16_f16(ah0, bl1, acc[0][1], 0, 0, 0);
        acc[1][0] = __builtin_amdgcn_mfma_f32_32x32x16_f16(ah1, bl0, acc[1][0], 0, 0, 0);
        acc[1][1] = __builtin_amdgcn_mfma_f32_32x32x16_f16(ah1, bl1, acc[1][1], 0, 0, 0);
        acc[0][0] = __builtin_amdgcn_mfma_f32_32x32x16_f16(al0, bh0, acc[0][0], 0, 0, 0);
        acc[0][1] = __builtin_amdgcn_mfma_f32_32x32x16_f16(al0, bh1, acc[0][1], 0, 0, 0);
        acc[1][0] = __builtin_amdgcn_mfma_f32_32x32x16_f16(al1, bh0, acc[1][0], 0, 0, 0);
        acc[1][1] = __builtin_amdgcn_mfma_f32_32x32x16_f16(al1, bh1, acc[1][1], 0, 0, 0);
    }

    float* out = xkp + (size_t)kz * BATCH * OUT_F;
#pragma unroll
    for (int mm = 0; mm < 2; ++mm)
#pragma unroll
        for (int nn = 0; nn < 2; ++nn) {
            const int col = n0 + wn + nn * 32 + l31;
#pragma unroll
            for (int r = 0; r < 16; ++r) {
                const int row = m0 + wm + mm * 32 + (r & 3) + 8 * (r >> 2) + 4 * half;
                out[(size_t)row * OUT_F + col] = acc[mm][nn][r];
            }
        }
}

// ---------------------------------------------------------------------------
// Plain NN GEMM fp32: decoded = encoded @ w  (one-shot)
// ---------------------------------------------------------------------------
__global__ __launch_bounds__(256)
void gemm_nn(const float* __restrict__ A, const float* __restrict__ B,
             float* __restrict__ C, int M, int N, int K) {
    __shared__ float As[BK][LDA];
    __shared__ float Bs[BK][LDB];
    const int tid = threadIdx.x;
    const int tx = tid & 15, ty = tid >> 4;
    const int m0 = blockIdx.y * BM;
    const int n0 = blockIdx.x * BN;
    const int lr = tid >> 2;
    const int lk = (tid & 3) * 4;
    const int kb = tid >> 4;
    const int nb = (tid & 15) * 4;

    float acc[TM][TN] = {};

    for (int k0 = 0; k0 < K; k0 += BK) {
        const float4 a4 = *(const float4*)&A[(size_t)(m0 + lr) * K + k0 + lk];
        const float4 b4 = *(const float4*)&B[(size_t)(k0 + kb) * N + n0 + nb];
        __syncthreads();
        As[lk + 0][lr] = a4.x; As[lk + 1][lr] = a4.y; As[lk + 2][lr] = a4.z; As[lk + 3][lr] = a4.w;
        *(float4*)&Bs[kb][nb] = b4;
        __syncthreads();
#pragma unroll
        for (int kk = 0; kk < BK; ++kk) {
            const float4 av = *(const float4*)&As[kk][ty * TM];
            const float4 bv = *(const float4*)&Bs[kk][tx * TN];
            const float ar[4] = {av.x, av.y, av.z, av.w};
            const float br[4] = {bv.x, bv.y, bv.z, bv.w};
#pragma unroll
            for (int i = 0; i < TM; ++i)
#pragma unroll
                for (int j = 0; j < TN; ++j)
                    acc[i][j] = fmaf(ar[i], br[j], acc[i][j]);
        }
    }
#pragma unroll
    for (int i = 0; i < TM; ++i) {
        float4 o = make_float4(acc[i][0], acc[i][1], acc[i][2], acc[i][3]);
        *(float4*)&C[(size_t)(m0 + ty * TM + i) * N + n0 + tx * TN] = o;
    }
}

// ---------------------------------------------------------------------------
// Update: xk = sum of 4 K-split partials; softshrink; u update; conv check;
// write next-iteration A_eff split (Ah/Al). One block per row.
// ---------------------------------------------------------------------------
__global__ __launch_bounds__(256)
void update_kernel(const float* __restrict__ xkp, const float* __restrict__ Ab,
                   float* __restrict__ v, float* __restrict__ u,
                   float* __restrict__ enc, _Float16* __restrict__ Ah,
                   _Float16* __restrict__ Al, int* __restrict__ solved) {
    const int row = blockIdx.x;
    if (solved[row]) return;
    const int t = threadIdx.x;
    constexpr size_t P = (size_t)BATCH * OUT_F;

    float vn_all[8];
    float dx2 = 0.f, xn2 = 0.f;
#pragma unroll
    for (int g = 0; g < 2; ++g) {
        const int c = g * 1024 + t * 4;
        const size_t off = (size_t)row * OUT_F + c;
        const float4 p0 = *(const float4*)&xkp[off];
        const float4 p1 = *(const float4*)&xkp[P + off];
        const float4 p2 = *(const float4*)&xkp[2 * P + off];
        const float4 p3 = *(const float4*)&xkp[3 * P + off];
        const float4 u4 = *(const float4*)&u[off];
        const float4 v4 = *(const float4*)&v[off];
        const float4 ab4 = *(const float4*)&Ab[off];
        float xs[4] = {p0.x + p1.x + p2.x + p3.x, p0.y + p1.y + p2.y + p3.y,
                       p0.z + p1.z + p2.z + p3.z, p0.w + p1.w + p2.w + p3.w};
        float us[4] = {u4.x, u4.y, u4.z, u4.w};
        float vs[4] = {v4.x, v4.y, v4.z, v4.w};
        float abs_[4] = {ab4.x, ab4.y, ab4.z, ab4.w};
        float vo[4], uo[4];
        half4 h, l;
#pragma unroll
        for (int j = 0; j < 4; ++j) {
            const float z = xs[j] + us[j];
            const float az = fabsf(z) - LAMBD;
            const float vnew = az > 0.f ? copysignf(az, z) : 0.f;
            const float unew = us[j] + xs[j] - vnew;
            const float d = vnew - vs[j];
            dx2 += d * d;
            xn2 += vnew * vnew;
            vo[j] = vnew; uo[j] = unew;
            vn_all[g * 4 + j] = vnew;
            const float aeff = abs_[j] + vnew - unew;
            const _Float16 hi = (_Float16)aeff;
            h[j] = hi;
            l[j] = (_Float16)(aeff - (float)hi);
        }
        *(float4*)&v[off] = make_float4(vo[0], vo[1], vo[2], vo[3]);
        *(float4*)&u[off] = make_float4(uo[0], uo[1], uo[2], uo[3]);
        *(half4*)&Ah[off] = h;
        *(half4*)&Al[off] = l;
    }

#pragma unroll
    for (int o = 32; o > 0; o >>= 1) {
        dx2 += __shfl_down(dx2, o);
        xn2 += __shfl_down(xn2, o);
    }
    __shared__ float sdx[4], sxn[4];
    __shared__ float s_conv;
    if ((t & 63) == 0) { sdx[t >> 6] = dx2; sxn[t >> 6] = xn2; }
    __syncthreads();
    if (t == 0) {
        const float dxt = sqrtf(sdx[0] + sdx[1] + sdx[2] + sdx[3]);
        const float xnt = sqrtf(sxn[0] + sxn[1] + sxn[2] + sxn[3]);
        const bool conv = (dxt / xnt) < TOL;   // NaN -> false, matches jnp
        s_conv = conv ? 1.f : 0.f;
        if (conv) solved[row] = 1;
    }
    __syncthreads();
    if (s_conv != 0.f) {
#pragma unroll
        for (int g = 0; g < 2; ++g) {
            const int c = g * 1024 + t * 4;
            *(float4*)&enc[(size_t)row * OUT_F + c] =
                make_float4(vn_all[g * 4], vn_all[g * 4 + 1], vn_all[g * 4 + 2], vn_all[g * 4 + 3]);
        }
    }
}

// ---------------------------------------------------------------------------
extern "C" void kernel_launch(void* const* d_in, const int* in_sizes, int n_in,
                              void* d_out, int out_size, void* d_ws, size_t ws_size,
                              hipStream_t stream) {
    (void)in_sizes; (void)n_in; (void)out_size; (void)ws_size;
    const float* x    = (const float*)d_in[0];   // 1024 x 1024
    const float* w    = (const float*)d_in[1];   // 2048 x 1024
    const float* Minv = (const float*)d_in[2];   // 2048 x 2048

    float* enc = (float*)d_out;                  // 1024 x 2048
    float* dec = enc + (size_t)BATCH * OUT_F;    // 1024 x 1024

    constexpr size_t P = (size_t)BATCH * OUT_F;  // 2M elements
    float* Ab  = (float*)d_ws;                   // 2M f32
    float* v   = Ab + P;                         // 2M f32
    float* u   = v + P;                          // 2M f32
    float* xkp = u + P;                          // 4 x 2M f32
    _Float16* Ah  = (_Float16*)(xkp + 4 * P);    // 2M f16
    _Float16* Al  = Ah + P;                      // 2M f16
    _Float16* BhT = Al + P;                      // 4M f16
    _Float16* BlT = BhT + (size_t)OUT_F * OUT_F; // 4M f16
    int* solved = (int*)(BlT + (size_t)OUT_F * OUT_F);

    {
        const int n4 = BATCH * OUT_F / 4;
        init_kernel<<<(n4 + 255) / 256, 256, 0, stream>>>(
            (float4*)v, (float4*)u, (float4*)enc, solved);
    }

    // one-shot: split+transpose M_inv
    split_b_kernel<<<dim3(OUT_F / 32, OUT_F / 32), 256, 0, stream>>>(Minv, BhT, BlT);

    // Ab = x @ w^T, plus initial Aeff split (v=u=0)
    gemm_nt<<<dim3(OUT_F / BN, BATCH / BM), 256, 0, stream>>>(x, w, Ab, Ah, Al,
                                                              BATCH, OUT_F, IN_F);

    for (int it = 0; it < MAX_ITERS; ++it) {
        xk_mfma<<<dim3(OUT_F / 128, BATCH / 128, KSPLIT), 256, 0, stream>>>(
            Ah, Al, BhT, BlT, xkp, solved);
        update_kernel<<<BATCH, 256, 0, stream>>>(xkp, Ab, v, u, enc, Ah, Al, solved);
    }

    // decoded = encoded @ w
    gemm_nn<<<dim3(IN_F / BN, BATCH / BM), 256, 0, stream>>>(enc, w, dec, BATCH, IN_F, OUT_F);
}